// Round 8
// baseline (83.692 us; speedup 1.0000x reference)
//
#include <hip/hip_runtime.h>
#include <cmath>

#define THREADS 256
#define QC 24000
#define NQ4 (QC / 4)
#define NCLS 80
#define NTOP 300
#define NHIST 4096
#define CAP 1024

typedef unsigned long long ull;
typedef float f32x4 __attribute__((ext_vector_type(4)));

// monotonic unsigned key for fp32 (total order matching float compare)
__device__ __forceinline__ unsigned fkey(float x) {
    unsigned b = __float_as_uint(x);
    return (b & 0x80000000u) ? ~b : (b | 0x80000000u);
}
__device__ __forceinline__ float fkey_inv(unsigned key) {
    unsigned b = (key & 0x80000000u) ? (key & 0x7fffffffu) : ~key;
    return __uint_as_float(b);
}
// Replicate float32 sigmoid: 1/(1+expf(-x)); double exp rounds to CR expf.
__device__ __forceinline__ float sigmoid_ref(float x) {
    float ef = (float)exp(-(double)x);
    return 1.0f / (1.0f + ef);
}

// Speculative static threshold: rank-300 logit ~2.24 for this data; 2.11
// keeps ~420 +- 20 candidates/row. Checked on-device; exact histogram
// fallback if any row violates [NTOP, CAP].
#define T0 2.11f

// single-wave sigmoid + bitonic sort (descending on (score,~idx)); no barriers
__device__ __forceinline__ void sort_wave(ull* __restrict__ c, int nc, int lane) {
    const int npad = (nc > 512) ? 1024 : 512;
    for (int sl = lane; sl < npad; sl += 64) {
        ull v = 0ull;
        if (sl < nc) {
            ull cc = c[sl];
            float sc = sigmoid_ref(fkey_inv((unsigned)(cc >> 32)));
            v = ((ull)__float_as_uint(sc) << 32) | (cc & 0xffffffffull);
        }
        c[sl] = v;
    }
    const int npairs = npad >> 1;
    for (int k = 2; k <= npad; k <<= 1) {
        for (int j = k >> 1; j > 0; j >>= 1) {
            for (int p = lane; p < npairs; p += 64) {
                int u = ((p & ~(j - 1)) << 1) | (p & (j - 1));
                int v2 = u | j;
                ull a = c[u], b = c[v2];
                bool desc = (u & k) == 0;
                if (desc ? (a < b) : (a > b)) { c[u] = b; c[v2] = a; }
            }
        }
    }
}

__global__ __launch_bounds__(THREADS, 4) void postproc_kernel(
    const float* __restrict__ logits,   // [B, 300, 80]
    const float* __restrict__ pboxes,   // [B, 300, 4]
    const float* __restrict__ osizes,   // [B, 2]
    float* __restrict__ out_boxes,      // [B, 300, 4]
    float* __restrict__ out_labels,     // [B, 300]
    float* __restrict__ out_scores,     // [B, 300]
    int B)
{
    const int b0 = blockIdx.x * 2;
    const int nrows = (B - b0 >= 2) ? 2 : 1;
    const int tid = threadIdx.x;
    const int lane = tid & 63;
    const int wid = tid >> 6;

    __shared__ ull cand[2][CAP];            // 16 KB
    __shared__ unsigned hist[NHIST / 2];    // 8 KB packed u16 (fallback only)
    __shared__ unsigned wsum[THREADS / 64];
    __shared__ int s_nc[2];

    if (tid < 2) s_nc[tid] = 0;
    __syncthreads();

    auto pushe = [&](int r, float x, int e) {
        if (x >= T0) {
            int p = atomicAdd(&s_nc[r], 1);
            if (p < CAP)
                cand[r][p] = ((ull)fkey(x) << 32) | (ull)(~(unsigned)e);
        }
    };
    auto handle = [&](int r, f32x4 v, int i) {
        pushe(r, v.x, 4 * i);     pushe(r, v.y, 4 * i + 1);
        pushe(r, v.z, 4 * i + 2); pushe(r, v.w, 4 * i + 3);
    };
    // thread-set-parameterized streaming scan of one row
    auto scan_row = [&](int r, int start, int nthr) {
        const f32x4* __restrict__ row4 =
            (const f32x4*)(logits + (size_t)(b0 + r) * QC);
        int i = start;
        for (; i + 3 * nthr < NQ4; i += 4 * nthr) {
            f32x4 a = __builtin_nontemporal_load(row4 + i);
            f32x4 b2 = __builtin_nontemporal_load(row4 + i + nthr);
            f32x4 c2 = __builtin_nontemporal_load(row4 + i + 2 * nthr);
            f32x4 d2 = __builtin_nontemporal_load(row4 + i + 3 * nthr);
            handle(r, a, i);            handle(r, b2, i + nthr);
            handle(r, c2, i + 2 * nthr); handle(r, d2, i + 3 * nthr);
        }
        for (; i < NQ4; i += nthr)
            handle(r, __builtin_nontemporal_load(row4 + i), i);
    };

    // exact histogram fallback for row r (ALL threads; block-uniform call)
    auto fallback = [&](int r) {
        const f32x4* __restrict__ row4 =
            (const f32x4*)(logits + (size_t)(b0 + r) * QC);
        for (int j = tid; j < NHIST / 2; j += THREADS) hist[j] = 0u;
        __syncthreads();
        for (int j = tid; j < NQ4; j += THREADS) {
            f32x4 v = row4[j];
            float vals[4] = {v.x, v.y, v.z, v.w};
            #pragma unroll
            for (int s = 0; s < 4; ++s) {
                unsigned bin = fkey(vals[s]) >> 20;
                atomicAdd(&hist[bin >> 1], (bin & 1) ? 0x10000u : 1u);
            }
        }
        __syncthreads();
        const int CHUNK = NHIST / THREADS;          // 16
        const int base = NHIST - 1 - tid * CHUNK;
        unsigned partial = 0;
        #pragma unroll
        for (int s = 0; s < CHUNK; ++s) {
            int bin = base - s;
            partial += (hist[bin >> 1] >> ((bin & 1) * 16)) & 0xffffu;
        }
        unsigned run = partial;
        #pragma unroll
        for (int d = 1; d < 64; d <<= 1) {
            unsigned v = __shfl_up(run, d, 64);
            if (lane >= d) run += v;
        }
        if (lane == 63) wsum[tid >> 6] = run;
        __syncthreads();
        unsigned off = 0;
        for (int w = 0; w < (tid >> 6); ++w) off += wsum[w];
        unsigned incl = run + off, excl = incl - partial;
        __shared__ unsigned s_thresh;
        if (excl < NTOP && incl >= NTOP) {
            unsigned cum = excl;
            #pragma unroll
            for (int s = 0; s < CHUNK; ++s) {
                int bin = base - s;
                cum += (hist[bin >> 1] >> ((bin & 1) * 16)) & 0xffffu;
                if (cum >= NTOP) { s_thresh = (unsigned)bin << 20; break; }
            }
        }
        if (tid == 0) s_nc[r] = 0;
        __syncthreads();
        const unsigned T = s_thresh;
        for (int j = tid; j < NQ4; j += THREADS) {
            f32x4 v = row4[j];
            float vals[4] = {v.x, v.y, v.z, v.w};
            #pragma unroll
            for (int s = 0; s < 4; ++s) {
                unsigned kk = fkey(vals[s]);
                if (kk >= T) {
                    int pos = atomicAdd(&s_nc[r], 1);
                    if (pos < CAP)
                        cand[r][pos] = ((ull)kk << 32)
                                     | (ull)(~(unsigned)(4 * j + s));
                }
            }
        }
        __syncthreads();
    };

    // emit top-300 of row r using a thread subset [etid in 0..nthr)
    auto emit_row = [&](int r, int etid, int nthr) {
        const int row = b0 + r;
        const float o0 = osizes[2 * row], o1 = osizes[2 * row + 1];
        const float4* __restrict__ pb4 = (const float4*)pboxes + (size_t)row * NTOP;
        float4* __restrict__ ob4 = (float4*)out_boxes + (size_t)row * NTOP;
        for (int rk = etid; rk < NTOP; rk += nthr) {
            ull c = cand[r][rk];
            float sc = __uint_as_float((unsigned)(c >> 32));
            unsigned idx = ~((unsigned)c);
            unsigned q = idx / NCLS;
            unsigned cls = idx - q * NCLS;
            out_scores[(size_t)row * NTOP + rk] = sc;
            out_labels[(size_t)row * NTOP + rk] = (float)cls;
            float4 pb = pb4[q];
            float4 ob;
            ob.x = (pb.x - 0.5f * pb.z) * o0;
            ob.y = (pb.y - 0.5f * pb.w) * o1;
            ob.z = (pb.x + 0.5f * pb.z) * o0;
            ob.w = (pb.y + 0.5f * pb.w) * o1;
            ob4[rk] = ob;
        }
    };

    // ---- P0: all waves scan row0 ----
    scan_row(0, tid, THREADS);
    __syncthreads();
    if (s_nc[0] < NTOP || s_nc[0] > CAP) fallback(0);   // uniform branch
    __syncthreads();
    const int nc0 = min(s_nc[0], CAP);

    // ---- P1: wave0 sorts row0; waves 1-3 scan row1 ----
    if (wid == 0) {
        sort_wave(cand[0], nc0, lane);
    } else if (nrows == 2) {
        scan_row(1, tid - 64, THREADS - 64);
    }
    __syncthreads();
    if (nrows == 2 && (s_nc[1] < NTOP || s_nc[1] > CAP)) fallback(1);
    __syncthreads();
    const int nc1 = (nrows == 2) ? min(s_nc[1], CAP) : 0;

    // ---- P2: wave1 sorts row1; waves 0,2,3 emit row0 ----
    if (wid == 1) {
        if (nrows == 2) sort_wave(cand[1], nc1, lane);
    } else {
        int etid = (wid == 0) ? lane : (64 + (wid - 2) * 64 + lane);  // 0..191
        emit_row(0, etid, 192);
    }
    __syncthreads();

    // ---- P3: all emit row1 ----
    if (nrows == 2) emit_row(1, tid, THREADS);
}

extern "C" void kernel_launch(void* const* d_in, const int* in_sizes, int n_in,
                              void* d_out, int out_size, void* d_ws, size_t ws_size,
                              hipStream_t stream) {
    const float* logits = (const float*)d_in[0];
    const float* pboxes = (const float*)d_in[1];
    const float* osizes = (const float*)d_in[2];
    const int B = in_sizes[2] / 2;

    float* out_boxes  = (float*)d_out;                       // B*300*4
    float* out_labels = out_boxes + (size_t)B * NTOP * 4;    // B*300
    float* out_scores = out_labels + (size_t)B * NTOP;       // B*300

    const int nblk = (B + 1) / 2;
    hipLaunchKernelGGL(postproc_kernel, dim3(nblk), dim3(THREADS), 0, stream,
                       logits, pboxes, osizes, out_boxes, out_labels, out_scores, B);
}

// Round 9
// 63.273 us; speedup vs baseline: 1.3227x; 1.3227x over previous
//
#include <hip/hip_runtime.h>
#include <cmath>

#define THREADS 256
#define QC 24000
#define NQ4 (QC / 4)
#define NCLS 80
#define NTOP 300
#define NHIST 4096
#define CAP 1024

typedef unsigned long long ull;
typedef float f32x4 __attribute__((ext_vector_type(4)));

// monotonic unsigned key for fp32 (total order matching float compare)
__device__ __forceinline__ unsigned fkey(float x) {
    unsigned b = __float_as_uint(x);
    return (b & 0x80000000u) ? ~b : (b | 0x80000000u);
}
__device__ __forceinline__ float fkey_inv(unsigned key) {
    unsigned b = (key & 0x80000000u) ? (key & 0x7fffffffu) : ~key;
    return __uint_as_float(b);
}
// Replicate float32 sigmoid: 1/(1+expf(-x)); double exp rounds to CR expf.
__device__ __forceinline__ float sigmoid_ref(float x) {
    float ef = (float)exp(-(double)x);
    return 1.0f / (1.0f + ef);
}

// Speculative static threshold: rank-300 logit ~2.24 for this data; 2.11
// keeps ~420 +- 20 candidates/row. Checked on-device; exact histogram
// fallback if any row violates [NTOP, CAP].
#define T0 2.11f

__global__ __launch_bounds__(THREADS, 4) void postproc_kernel(
    const float* __restrict__ logits,   // [B, 300, 80]
    const float* __restrict__ pboxes,   // [B, 300, 4]
    const float* __restrict__ osizes,   // [B, 2]
    float* __restrict__ out_boxes,      // [B, 300, 4]
    float* __restrict__ out_labels,     // [B, 300]
    float* __restrict__ out_scores,     // [B, 300]
    int B)
{
    const int b0 = blockIdx.x * 2;
    const int nrows = (B - b0 >= 2) ? 2 : 1;
    const int tid = threadIdx.x;
    const int lane = tid & 63;

    __shared__ ull cand[2][CAP];            // 16 KB (buf per local row)
    __shared__ unsigned hist[NHIST / 2];    // 8 KB packed u16 (fallback only)
    __shared__ unsigned wsum[THREADS / 64];
    __shared__ int s_nc[2];
    __shared__ unsigned s_thresh;

    if (tid < 2) s_nc[tid] = 0;
    __syncthreads();

    // push element e of local row t's global row if above threshold
    auto pushe = [&](int t, float x, int e) {
        if (x >= T0) {
            int p = atomicAdd(&s_nc[t], 1);
            if (p < CAP)
                cand[t][p] = ((ull)fkey(x) << 32) | (ull)(~(unsigned)e);
        }
    };

    // plain full-speed scan of local row t
    auto scan_plain = [&](int t) {
        const f32x4* __restrict__ r4 =
            (const f32x4*)(logits + (size_t)(b0 + t) * QC);
        int i = tid;
        for (; i + 3 * THREADS < NQ4; i += 4 * THREADS) {
            f32x4 a = __builtin_nontemporal_load(r4 + i);
            f32x4 b2 = __builtin_nontemporal_load(r4 + i + THREADS);
            f32x4 c2 = __builtin_nontemporal_load(r4 + i + 2 * THREADS);
            f32x4 d2 = __builtin_nontemporal_load(r4 + i + 3 * THREADS);
            pushe(t, a.x, 4*i); pushe(t, a.y, 4*i+1); pushe(t, a.z, 4*i+2); pushe(t, a.w, 4*i+3);
            int i1 = i + THREADS;
            pushe(t, b2.x, 4*i1); pushe(t, b2.y, 4*i1+1); pushe(t, b2.z, 4*i1+2); pushe(t, b2.w, 4*i1+3);
            int i2 = i + 2 * THREADS;
            pushe(t, c2.x, 4*i2); pushe(t, c2.y, 4*i2+1); pushe(t, c2.z, 4*i2+2); pushe(t, c2.w, 4*i2+3);
            int i3 = i + 3 * THREADS;
            pushe(t, d2.x, 4*i3); pushe(t, d2.y, 4*i3+1); pushe(t, d2.z, 4*i3+2); pushe(t, d2.w, 4*i3+3);
        }
        for (; i < NQ4; i += THREADS) {
            f32x4 a = __builtin_nontemporal_load(r4 + i);
            pushe(t, a.x, 4*i); pushe(t, a.y, 4*i+1); pushe(t, a.z, 4*i+2); pushe(t, a.w, 4*i+3);
        }
    };

    // exact histogram fallback for local row t (block-uniform call)
    auto fallback = [&](int t) {
        const f32x4* __restrict__ r4 =
            (const f32x4*)(logits + (size_t)(b0 + t) * QC);
        for (int j = tid; j < NHIST / 2; j += THREADS) hist[j] = 0u;
        __syncthreads();
        for (int j = tid; j < NQ4; j += THREADS) {
            f32x4 v = r4[j];
            float vals[4] = {v.x, v.y, v.z, v.w};
            #pragma unroll
            for (int s = 0; s < 4; ++s) {
                unsigned bin = fkey(vals[s]) >> 20;
                atomicAdd(&hist[bin >> 1], (bin & 1) ? 0x10000u : 1u);
            }
        }
        __syncthreads();
        const int CHUNK = NHIST / THREADS;          // 16
        const int base = NHIST - 1 - tid * CHUNK;
        unsigned partial = 0;
        #pragma unroll
        for (int s = 0; s < CHUNK; ++s) {
            int bin = base - s;
            partial += (hist[bin >> 1] >> ((bin & 1) * 16)) & 0xffffu;
        }
        unsigned run = partial;
        #pragma unroll
        for (int d = 1; d < 64; d <<= 1) {
            unsigned v = __shfl_up(run, d, 64);
            if (lane >= d) run += v;
        }
        if (lane == 63) wsum[tid >> 6] = run;
        __syncthreads();
        unsigned off = 0;
        for (int w = 0; w < (tid >> 6); ++w) off += wsum[w];
        unsigned incl = run + off, excl = incl - partial;
        if (excl < NTOP && incl >= NTOP) {
            unsigned cum = excl;
            #pragma unroll
            for (int s = 0; s < CHUNK; ++s) {
                int bin = base - s;
                cum += (hist[bin >> 1] >> ((bin & 1) * 16)) & 0xffffu;
                if (cum >= NTOP) { s_thresh = (unsigned)bin << 20; break; }
            }
        }
        if (tid == 0) s_nc[t] = 0;
        __syncthreads();
        const unsigned T = s_thresh;
        for (int j = tid; j < NQ4; j += THREADS) {
            f32x4 v = r4[j];
            float vals[4] = {v.x, v.y, v.z, v.w};
            #pragma unroll
            for (int s = 0; s < 4; ++s) {
                unsigned kk = fkey(vals[s]);
                if (kk >= T) {
                    int pos = atomicAdd(&s_nc[t], 1);
                    if (pos < CAP)
                        cand[t][pos] = ((ull)kk << 32)
                                     | (ull)(~(unsigned)(4 * j + s));
                }
            }
        }
        __syncthreads();
    };

    auto emit_one = [&](int t, int rk) {
        const int row = b0 + t;
        ull c = cand[t][rk];
        float sc = __uint_as_float((unsigned)(c >> 32));
        unsigned idx = ~((unsigned)c);
        unsigned q = idx / NCLS;
        unsigned cls = idx - q * NCLS;
        const float o0 = osizes[2 * row], o1 = osizes[2 * row + 1];
        out_scores[(size_t)row * NTOP + rk] = sc;
        out_labels[(size_t)row * NTOP + rk] = (float)cls;
        float4 pb = ((const float4*)pboxes + (size_t)row * NTOP)[q];
        float4 ob;
        ob.x = (pb.x - 0.5f * pb.z) * o0;
        ob.y = (pb.y - 0.5f * pb.w) * o1;
        ob.z = (pb.x + 0.5f * pb.z) * o0;
        ob.w = (pb.y + 0.5f * pb.w) * o1;
        ((float4*)out_boxes + (size_t)row * NTOP)[rk] = ob;
    };
    auto emit_plain = [&](int t) {
        for (int rk = tid; rk < NTOP; rk += THREADS) emit_one(t, rk);
    };

    // sigmoid-convert + zero-pad buf t to npad (each thread owns its slots)
    auto sig_pad = [&](int t, int nc, int npad) {
        for (int sl = tid; sl < npad; sl += THREADS) {
            ull v = 0ull;
            if (sl < nc) {
                ull c = cand[t][sl];
                float sc = sigmoid_ref(fkey_inv((unsigned)(c >> 32)));
                v = ((ull)__float_as_uint(sc) << 32) | (c & 0xffffffffull);
            }
            cand[t][sl] = v;
        }
    };

    // guarded nontemporal load; OOB -> below-threshold sentinel
    auto ldg4 = [&](const f32x4* r4, int i) -> f32x4 {
        if (i < NQ4) return __builtin_nontemporal_load(r4 + i);
        f32x4 z; z.x = z.y = z.z = z.w = -1e30f; return z;
    };

    // sort buf[cur]; optionally interleave scan of local row (cur^1) or
    // emit of local row (cur^1) into the stage stream
    auto phase = [&](int cur, int nc, bool do_scan, bool do_emit) {
        int npad = (nc > 512) ? 1024 : 512;
        sig_pad(cur, nc, npad);
        __syncthreads();
        if (npad == 512) {
            const int oth = cur ^ 1;
            const f32x4* __restrict__ r4s =
                (const f32x4*)(logits + (size_t)(b0 + oth) * QC);
            f32x4 va, vb, vc;           // in-flight scan group (3 chunks)
            int s = 0;
            for (int k = 2; k <= 512; k <<= 1) {
                for (int j = k >> 1; j > 0; j >>= 1) {
                    if (do_scan && (s % 3) == 0) {
                        int g = s / 3;
                        if (g >= 1 && g <= 8) {     // push group g-1 (loaded 3 stages ago)
                            int base = (g - 1) * 768;
                            int ia = base + tid, ib = base + 256 + tid, ic = base + 512 + tid;
                            pushe(oth, va.x, 4*ia); pushe(oth, va.y, 4*ia+1);
                            pushe(oth, va.z, 4*ia+2); pushe(oth, va.w, 4*ia+3);
                            pushe(oth, vb.x, 4*ib); pushe(oth, vb.y, 4*ib+1);
                            pushe(oth, vb.z, 4*ib+2); pushe(oth, vb.w, 4*ib+3);
                            pushe(oth, vc.x, 4*ic); pushe(oth, vc.y, 4*ic+1);
                            pushe(oth, vc.z, 4*ic+2); pushe(oth, vc.w, 4*ic+3);
                        }
                        if (g <= 7) {               // issue group g
                            int base = g * 768;
                            va = ldg4(r4s, base + tid);
                            vb = ldg4(r4s, base + 256 + tid);
                            vc = ldg4(r4s, base + 512 + tid);
                        }
                    }
                    if (do_emit) {
                        if (s == 1) emit_one(cur ^ 1, tid);
                        if (s == 2 && tid < NTOP - 256) emit_one(cur ^ 1, 256 + tid);
                    }
                    // bitonic stage: 256 disjoint pairs, 1 per thread
                    int u = ((tid & ~(j - 1)) << 1) | (tid & (j - 1));
                    int uxj = u | j;
                    ull a = cand[cur][u], c = cand[cur][uxj];
                    bool desc = (u & k) == 0;
                    if (desc ? (a < c) : (a > c)) { cand[cur][u] = c; cand[cur][uxj] = a; }
                    __syncthreads();
                    ++s;
                }
            }
        } else {
            // rare: plain 1024 bitonic, then un-overlapped scan/emit
            for (int k = 2; k <= 1024; k <<= 1) {
                for (int j = k >> 1; j > 0; j >>= 1) {
                    for (int t = tid; t < 512; t += THREADS) {
                        int u = ((t & ~(j - 1)) << 1) | (t & (j - 1));
                        int uxj = u | j;
                        ull a = cand[cur][u], c = cand[cur][uxj];
                        bool desc = (u & k) == 0;
                        if (desc ? (a < c) : (a > c)) { cand[cur][u] = c; cand[cur][uxj] = a; }
                    }
                    __syncthreads();
                }
            }
            if (do_scan) { scan_plain(cur ^ 1); __syncthreads(); }
            if (do_emit) emit_plain(cur ^ 1);
        }
    };

    // ---- prologue: scan row0 plain ----
    scan_plain(0);
    __syncthreads();
    if (s_nc[0] < NTOP || s_nc[0] > CAP) fallback(0);
    __syncthreads();
    const int nc0 = min(s_nc[0], CAP);

    if (nrows == 2) {
        // phase0: sort row0  ||  scan row1
        phase(0, nc0, true, false);
        if (s_nc[1] < NTOP || s_nc[1] > CAP) fallback(1);
        __syncthreads();
        const int nc1 = min(s_nc[1], CAP);
        // phase1: sort row1  ||  emit row0
        phase(1, nc1, false, true);
        // epilogue
        emit_plain(1);
    } else {
        phase(0, nc0, false, false);
        emit_plain(0);
    }
}

extern "C" void kernel_launch(void* const* d_in, const int* in_sizes, int n_in,
                              void* d_out, int out_size, void* d_ws, size_t ws_size,
                              hipStream_t stream) {
    const float* logits = (const float*)d_in[0];
    const float* pboxes = (const float*)d_in[1];
    const float* osizes = (const float*)d_in[2];
    const int B = in_sizes[2] / 2;

    float* out_boxes  = (float*)d_out;                       // B*300*4
    float* out_labels = out_boxes + (size_t)B * NTOP * 4;    // B*300
    float* out_scores = out_labels + (size_t)B * NTOP;       // B*300

    const int nblk = (B + 1) / 2;
    hipLaunchKernelGGL(postproc_kernel, dim3(nblk), dim3(THREADS), 0, stream,
                       logits, pboxes, osizes, out_boxes, out_labels, out_scores, B);
}